// Round 2
// baseline (14630.679 us; speedup 1.0000x reference)
//
#include <hip/hip_runtime.h>

#define SEG_EPS 1e-5f

// ---------------------------------------------------------------------------
// Row-windowed conv 3x3, reflect-pad-1 (at logical HxW), bias, optional relu.
// NCHW / OIHW, f32.
//   in  : band buffer holding logical rows [in_row0, in_row0+in_rows), width W
//   out : band buffer for logical rows [ob_row0, ob_row0+ob_rows)
//   computes logical rows [out_row0, out_row0+out_rows)
// grid: (W/16, ceil(out_rows/16), B * Cout/CO_PER), block (16,16).
// ---------------------------------------------------------------------------
template<int CO_PER, int RELU>
__global__ __launch_bounds__(256) void conv3x3_k(
    const float* __restrict__ in, const float* __restrict__ wgt,
    const float* __restrict__ bias, float* __restrict__ out,
    int Cin, int Cout, int H, int W,
    int in_row0, int in_rows, int out_row0, int out_rows,
    int ob_row0, int ob_rows) {
  const int wx = blockIdx.x * 16 + threadIdx.x;
  const int hy = out_row0 + blockIdx.y * 16 + threadIdx.y;
  const int nCo = Cout / CO_PER;
  const int co0 = (blockIdx.z % nCo) * CO_PER;
  const int b   = blockIdx.z / nCo;
  if (wx >= W || hy >= out_row0 + out_rows) return;

  // reflect-pad-1 at logical resolution
  const int hm = (hy == 0) ? 1 : hy - 1;
  const int hp = (hy == H - 1) ? H - 2 : hy + 1;
  const int wm = (wx == 0) ? 1 : wx - 1;
  const int wp = (wx == W - 1) ? W - 2 : wx + 1;

  const int ps = in_rows * W;  // input plane stride
  const float* inb = in + (size_t)b * Cin * ps;
  const int rm = (hm - in_row0) * W;
  const int r0 = (hy - in_row0) * W;
  const int rp = (hp - in_row0) * W;

  float acc[CO_PER];
#pragma unroll
  for (int u = 0; u < CO_PER; ++u) acc[u] = bias[co0 + u];

  const size_t wstride = (size_t)Cin * 9;
  const float* wbase = wgt + (size_t)co0 * wstride;

  for (int ci = 0; ci < Cin; ++ci) {
    const float* p = inb + (size_t)ci * ps;
    const float x00 = p[rm + wm], x01 = p[rm + wx], x02 = p[rm + wp];
    const float x10 = p[r0 + wm], x11 = p[r0 + wx], x12 = p[r0 + wp];
    const float x20 = p[rp + wm], x21 = p[rp + wx], x22 = p[rp + wp];
#pragma unroll
    for (int u = 0; u < CO_PER; ++u) {
      const float* q = wbase + u * wstride + (size_t)ci * 9;  // block-uniform
      acc[u] += x00 * q[0] + x01 * q[1] + x02 * q[2]
              + x10 * q[3] + x11 * q[4] + x12 * q[5]
              + x20 * q[6] + x21 * q[7] + x22 * q[8];
    }
  }

  const size_t ops = (size_t)ob_rows * W;  // output plane stride
  float* ob = out + ((size_t)b * Cout + co0) * ops + (size_t)(hy - ob_row0) * W + wx;
#pragma unroll
  for (int u = 0; u < CO_PER; ++u) {
    float v = acc[u];
    if (RELU) v = fmaxf(v, 0.f);
    ob[u * ops] = v;
  }
}

// ---------------------------------------------------------------------------
// per-class (8) masked instance norm, closed form:
//   out[p] = x[p] * rs[cls(p)] - sum_c mu_c * rs_c
// with mu_c = S_c/N over the WHOLE plane. One block per (b,channel) plane.
// Full planes only; H=W=2^logW; seg is 64x64 int32, nearest = >>(logW-6).
// ---------------------------------------------------------------------------
__global__ __launch_bounds__(256) void seg_norm_k(
    const float* __restrict__ x, const int* __restrict__ seg,
    float* __restrict__ out, int C, int logW) {
  const int bc = blockIdx.x;
  const int b = bc / C;
  const int W = 1 << logW;
  const int N = W * W;
  const int shift = logW - 6;
  const float* xp = x + (size_t)bc * N;
  const int* sp = seg + b * 4096;

  float S[8] = {0, 0, 0, 0, 0, 0, 0, 0};
  float Q[8] = {0, 0, 0, 0, 0, 0, 0, 0};
  for (int i = threadIdx.x; i < N; i += 256) {
    const int h = i >> logW, w = i & (W - 1);
    const int cls = sp[((h >> shift) << 6) + (w >> shift)];
    const float v = xp[i];
#pragma unroll
    for (int c = 0; c < 8; ++c) {
      const bool m = (cls == c);
      S[c] += m ? v : 0.f;
      Q[c] += m ? v * v : 0.f;
    }
  }
#pragma unroll
  for (int c = 0; c < 8; ++c) {
    for (int o = 32; o > 0; o >>= 1) {
      S[c] += __shfl_down(S[c], o, 64);
      Q[c] += __shfl_down(Q[c], o, 64);
    }
  }
  __shared__ float sS[4][8], sQ[4][8];
  __shared__ float rs[8];
  __shared__ float Ksh;
  const int lane = threadIdx.x & 63, wid = threadIdx.x >> 6;
  if (lane == 0) {
#pragma unroll
    for (int c = 0; c < 8; ++c) { sS[wid][c] = S[c]; sQ[wid][c] = Q[c]; }
  }
  __syncthreads();
  if (threadIdx.x == 0) {
    float K = 0.f;
    const float invN = 1.0f / (float)N;
#pragma unroll
    for (int c = 0; c < 8; ++c) {
      const float s = sS[0][c] + sS[1][c] + sS[2][c] + sS[3][c];
      const float q = sQ[0][c] + sQ[1][c] + sQ[2][c] + sQ[3][c];
      const float mu = s * invN;
      const float var = q * invN - mu * mu;
      const float r = rsqrtf(var + SEG_EPS);
      rs[c] = r;
      K += mu * r;
    }
    Ksh = K;
  }
  __syncthreads();
  const float K = Ksh;
  float* op = out + (size_t)bc * N;
  for (int i = threadIdx.x; i < N; i += 256) {
    const int h = i >> logW, w = i & (W - 1);
    const int cls = sp[((h >> shift) << 6) + (w >> shift)];
    op[i] = xp[i] * rs[cls] - K;
  }
}

// ---------------------------------------------------------------------------
// Row-windowed bilinear 2x upsample (jax.image.resize 'bilinear' semantics).
// Reads FULL source (C planes of W x W, W = 1<<logW); writes logical output
// rows [out_row0, out_row0+out_rows) at resolution 2W into a band buffer.
// ---------------------------------------------------------------------------
__global__ __launch_bounds__(256) void up2_k(
    const float* __restrict__ in, float* __restrict__ out,
    int logW, int C, int out_row0, int out_rows) {
  const int W = 1 << logW;
  const int logW2 = logW + 1;
  const int W2 = W << 1;
  const int total = 4 * C * out_rows * W2;
  const int i = blockIdx.x * 256 + threadIdx.x;
  if (i >= total) return;
  const int ow = i & (W2 - 1);
  const int t = i >> logW2;       // = bc * out_rows + r
  const int r = t % out_rows;
  const int bc = t / out_rows;
  const int oh = out_row0 + r;

  int hlo = (oh - 1) >> 1;
  const float hf = (oh & 1) ? 0.25f : 0.75f;  // weight on hi
  int hhi = hlo + 1;
  hlo = max(hlo, 0); hhi = min(hhi, W - 1);
  int wlo = (ow - 1) >> 1;
  const float wf = (ow & 1) ? 0.25f : 0.75f;
  int whi = wlo + 1;
  wlo = max(wlo, 0); whi = min(whi, W - 1);

  const float* p = in + ((size_t)bc << (2 * logW));
  const float a  = p[(hlo << logW) + wlo], b2 = p[(hlo << logW) + whi];
  const float c  = p[(hhi << logW) + wlo], d2 = p[(hhi << logW) + whi];
  const float top = a + wf * (b2 - a);
  const float bot = c + wf * (d2 - c);
  out[(size_t)t * W2 + ow] = top + hf * (bot - top);
}

// ---------------------------------------------------------------------------
extern "C" void kernel_launch(void* const* d_in, const int* in_sizes, int n_in,
                              void* d_out, int out_size, void* d_ws, size_t ws_size,
                              hipStream_t stream) {
  const float* x   = (const float*)d_in[0];
  const int*   seg = (const int*)d_in[1];
  const float *w1 = (const float*)d_in[2],  *b1 = (const float*)d_in[3];
  const float *w2 = (const float*)d_in[4],  *b2 = (const float*)d_in[5];
  const float *w3 = (const float*)d_in[6],  *b3 = (const float*)d_in[7];
  const float *w4 = (const float*)d_in[8],  *b4 = (const float*)d_in[9];
  const float *w5 = (const float*)d_in[10], *b5 = (const float*)d_in[11];
  const float *w6 = (const float*)d_in[12], *b6 = (const float*)d_in[13];
  const float *w7 = (const float*)d_in[14], *b7 = (const float*)d_in[15];
  const float *w8 = (const float*)d_in[16], *b8 = (const float*)d_in[17];
  const float *wf = (const float*)d_in[18], *bf = (const float*)d_in[19];
  float* outp = (float*)d_out;

  // workspace layout (float offsets); peak usage = 128 MB
  float* ws = (float*)d_ws;
  const size_t MBf = 262144;  // floats per MB
  float* Ta = ws;              // conv1 out        [0,16) MB
  float* Tb = ws + 16 * MBf;   // segnorm64 out    [16,32)
  float* C1 = ws + 64 * MBf;   // up2 @128 out     [64,128)
  float* S0 = ws;              // 64MB slot        [0,64)
  float* S1 = ws + 64 * MBf;   // 64MB slot        [64,128)
  float* E  = ws + 64 * MBf;   // conv5 out (32MB) [64,96)
  float* F  = ws;              // segnorm128 (32MB)[0,32)
  float* U6 = ws + 32 * MBf;   // up2 band @256    [32,42)
  float* C6 = ws + 42 * MBf;   // conv6 band       [42,51)
  float* C7 = ws + 64 * MBf;   // conv7 out (64MB) [64,128)
  float* J  = ws;              // segnorm256 (64MB)[0,64)
  float* U8 = ws + 64 * MBf;   // up2 band @512    [64,82)
  float* V8 = ws + 82 * MBf;   // conv8 band       [82,99)

  const dim3 blk(16, 16);

  // ---- @64 ----
  conv3x3_k<4, 1><<<dim3(4, 4, 256), blk, 0, stream>>>(
      x, w1, b1, Ta, 512, 256, 64, 64, 0, 64, 0, 64, 0, 64);
  seg_norm_k<<<4 * 256, 256, 0, stream>>>(Ta, seg, Tb, 256, 6);

  // ---- up2 -> @128 (full), convs 2..5, segnorm ----
  up2_k<<<(4 * 256 * 128 * 256) / 256, 256, 0, stream>>>(Tb, C1, 6, 256, 0, 128);
  conv3x3_k<4, 1><<<dim3(8, 8, 256), blk, 0, stream>>>(
      C1, w2, b2, S0, 256, 256, 128, 128, 0, 128, 0, 128, 0, 128);
  conv3x3_k<4, 1><<<dim3(8, 8, 256), blk, 0, stream>>>(
      S0, w3, b3, S1, 256, 256, 128, 128, 0, 128, 0, 128, 0, 128);
  conv3x3_k<4, 1><<<dim3(8, 8, 256), blk, 0, stream>>>(
      S1, w4, b4, S0, 256, 256, 128, 128, 0, 128, 0, 128, 0, 128);
  conv3x3_k<4, 1><<<dim3(8, 8, 128), blk, 0, stream>>>(
      S0, w5, b5, E, 256, 128, 128, 128, 0, 128, 0, 128, 0, 128);
  seg_norm_k<<<4 * 128, 256, 0, stream>>>(E, seg, F, 128, 7);

  // ---- @256 stage, chain-banded: up2 -> conv6 -> conv7 (16 bands x 16 rows)
  for (int kb = 0; kb < 16; ++kb) {
    const int r0 = kb * 16;                       // conv7 output rows [r0, r0+16)
    const int Rlo = max(r0 - 1, 0), Rhi = min(r0 + 16, 255);  // conv6 rows, incl.
    const int rows6 = Rhi - Rlo + 1;
    const int Ulo = max(Rlo - 1, 0), Uhi = min(Rhi + 1, 255); // up2 rows, incl.
    const int rowsU = Uhi - Ulo + 1;
    up2_k<<<(4 * 128 * rowsU * 256 + 255) / 256, 256, 0, stream>>>(
        F, U6, 7, 128, Ulo, rowsU);
    conv3x3_k<4, 1><<<dim3(16, (rows6 + 15) / 16, 128), blk, 0, stream>>>(
        U6, w6, b6, C6, 128, 128, 256, 256, Ulo, rowsU, Rlo, rows6, Rlo, rows6);
    conv3x3_k<4, 1><<<dim3(16, 1, 64), blk, 0, stream>>>(
        C6, w7, b7, C7, 128, 64, 256, 256, Rlo, rows6, r0, 16, 0, 256);
  }
  seg_norm_k<<<4 * 64, 256, 0, stream>>>(C7, seg, J, 64, 8);

  // ---- @512 stage, chain-banded: up2 -> conv8 -> convf (16 bands x 32 rows)
  for (int kb = 0; kb < 16; ++kb) {
    const int r0 = kb * 32;                       // convf output rows [r0, r0+32)
    const int Rlo = max(r0 - 1, 0), Rhi = min(r0 + 32, 511);  // conv8 rows, incl.
    const int rows8 = Rhi - Rlo + 1;
    const int Ulo = max(Rlo - 1, 0), Uhi = min(Rhi + 1, 511); // up2 rows, incl.
    const int rowsU = Uhi - Ulo + 1;
    up2_k<<<(4 * 64 * rowsU * 512 + 255) / 256, 256, 0, stream>>>(
        J, U8, 8, 64, Ulo, rowsU);
    conv3x3_k<4, 1><<<dim3(32, (rows8 + 15) / 16, 64), blk, 0, stream>>>(
        U8, w8, b8, V8, 64, 64, 512, 512, Ulo, rowsU, Rlo, rows8, Rlo, rows8);
    conv3x3_k<3, 0><<<dim3(32, 2, 4), blk, 0, stream>>>(
        V8, wf, bf, outp, 64, 3, 512, 512, Rlo, rows8, r0, 32, 0, 512);
  }
}

// Round 3
// 2687.761 us; speedup vs baseline: 5.4434x; 5.4434x over previous
//
#include <hip/hip_runtime.h>

typedef unsigned int uint;
typedef unsigned short ushort;
typedef __bf16 bf16x8 __attribute__((ext_vector_type(8)));
typedef float f32x4 __attribute__((ext_vector_type(4)));
typedef uint u32x4 __attribute__((ext_vector_type(4)));
typedef ushort u16x4 __attribute__((ext_vector_type(4)));

__device__ __forceinline__ float bf_lo(uint u) { return __builtin_bit_cast(float, u << 16); }
__device__ __forceinline__ float bf_hi(uint u) { return __builtin_bit_cast(float, u & 0xFFFF0000u); }
__device__ __forceinline__ ushort f2bf(float f) {
  uint u = __builtin_bit_cast(uint, f);
  return (ushort)((u + 0x7FFFu + ((u >> 16) & 1u)) >> 16);
}

// ---------------------------------------------------------------------------
// MFMA implicit-GEMM 3x3 conv, reflect-pad-1, bias, optional relu.
// Activations NHWC bf16 (band buffers), weights prepacked [9][Cout][Cin] bf16.
// Block: 256 thr = 4 waves (2co x 2px). Tile: 64co x 64px (one output row seg).
// K-loop: ci chunks of 32; 9 taps x 4 mfma_f32_16x16x32_bf16 per wave per chunk.
// B staged in LDS [3 rows][66 px][32 ci] with XOR bank swizzle, double-buffered.
// ---------------------------------------------------------------------------
template<int RELU>
__global__ __launch_bounds__(256) void conv_mfma_k(
    const ushort* __restrict__ in, const ushort* __restrict__ wp,
    const float* __restrict__ bias, ushort* __restrict__ out,
    int Cin, int Cout, int H, int W,
    int in_row0, int in_rows, int out_row0, int ob_row0, int ob_rows) {
  __shared__ ushort lds[2][8192];  // 2 x 16KB (792 used slots + junk pad)
  const int tid = threadIdx.x;
  const int lane = tid & 63;
  const int wv = tid >> 6;
  const int wco = wv & 1, wpx = wv >> 1;
  const int wx0 = blockIdx.x * 64;
  const int h = out_row0 + blockIdx.y;
  const int nCoB = Cout >> 6;
  const int cob = (blockIdx.z % nCoB) * 64 + wco * 32;
  const int b = blockIdx.z / nCoB;

  int hs[3];
  hs[0] = (h == 0) ? 1 : h - 1;
  hs[1] = h;
  hs[2] = (h == H - 1) ? H - 2 : h + 1;

  // --- staging precompute: lane t covers LDS 16B slot t; slot=(r*66+px)*4+kg'
  const ushort* gsrc[4];
  uint lof[4];
#pragma unroll
  for (int p = 0; p < 4; ++p) {
    const int t = p * 256 + tid;
    const int px_g = t >> 2, kgs = t & 3;
    const int rr = px_g / 66;
    const int r = rr > 2 ? 2 : rr;
    const int px = px_g - rr * 66;          // junk region for t>=792, never read
    const int kg = kgs ^ ((px >> 1) & 3);   // inverse swizzle on global source
    int wsrc = wx0 + px - 1;
    wsrc = (wsrc < 0) ? 1 : (wsrc >= W ? W - 2 : wsrc);
    gsrc[p] = in + ((size_t)(b * in_rows + (hs[r] - in_row0)) * W + wsrc) * Cin + kg * 8;
    lof[p] = (uint)((p * 256 + wv * 64) * 8);  // wave-uniform LDS base (ushorts)
  }

  const int arow = lane & 15;
  const int akg = (lane >> 4) * 8;
  const int bpx0 = wpx * 32 + (lane & 15);
  const int bkg = lane >> 4;

  f32x4 acc00{}, acc01{}, acc10{}, acc11{};
  const int nch = Cin >> 5;

  auto stage = [&](int buf, int ci0) {
#pragma unroll
    for (int p = 0; p < 4; ++p) {
      __builtin_amdgcn_global_load_lds(
          (const __attribute__((address_space(1))) void*)(gsrc[p] + ci0),
          (__attribute__((address_space(3))) void*)(&lds[buf][lof[p]]), 16, 0, 0);
    }
  };
  auto compute = [&](int buf, int ci0) {
    const ushort* lb = &lds[buf][0];
#pragma unroll
    for (int r = 0; r < 3; ++r)
#pragma unroll
      for (int s = 0; s < 3; ++s) {
        const int t9 = r * 3 + s;
        const u32x4 a0r = *(const u32x4*)(wp + (size_t)(t9 * Cout + cob + arow) * Cin + akg + ci0);
        const u32x4 a1r = *(const u32x4*)(wp + (size_t)(t9 * Cout + cob + 16 + arow) * Cin + akg + ci0);
        const int px0 = bpx0 + s;
        const int px1 = px0 + 16;
        const int sl0 = (r * 66 + px0) * 4 + (bkg ^ ((px0 >> 1) & 3));
        const int sl1 = (r * 66 + px1) * 4 + (bkg ^ ((px1 >> 1) & 3));
        const u32x4 b0r = *(const u32x4*)(lb + sl0 * 8);
        const u32x4 b1r = *(const u32x4*)(lb + sl1 * 8);
        const bf16x8 a0 = __builtin_bit_cast(bf16x8, a0r);
        const bf16x8 a1 = __builtin_bit_cast(bf16x8, a1r);
        const bf16x8 b0 = __builtin_bit_cast(bf16x8, b0r);
        const bf16x8 b1 = __builtin_bit_cast(bf16x8, b1r);
        acc00 = __builtin_amdgcn_mfma_f32_16x16x32_bf16(a0, b0, acc00, 0, 0, 0);
        acc01 = __builtin_amdgcn_mfma_f32_16x16x32_bf16(a0, b1, acc01, 0, 0, 0);
        acc10 = __builtin_amdgcn_mfma_f32_16x16x32_bf16(a1, b0, acc10, 0, 0, 0);
        acc11 = __builtin_amdgcn_mfma_f32_16x16x32_bf16(a1, b1, acc11, 0, 0, 0);
      }
  };

  stage(0, 0);
  asm volatile("s_waitcnt vmcnt(0)" ::: "memory");
  __syncthreads();
  for (int c = 0; c < nch; ++c) {
    if (c + 1 < nch) stage((c + 1) & 1, (c + 1) * 32);
    compute(c & 1, c * 32);
    asm volatile("s_waitcnt vmcnt(0)" ::: "memory");
    __syncthreads();
  }

  // epilogue: D col=lane&15 (px), row=(lane>>4)*4+reg (co); 4 co contiguous -> 8B store
  const int hloc = h - ob_row0;
  const size_t rowbase = ((size_t)(b * ob_rows + hloc)) * W;
#define EPI(ACC, I, J)                                                          \
  {                                                                             \
    const int cofr = cob + (I) * 16 + (lane >> 4) * 4;                          \
    const int wpxj = wx0 + wpx * 32 + (J) * 16 + (lane & 15);                   \
    u16x4 pk;                                                                   \
    _Pragma("unroll") for (int g = 0; g < 4; ++g) {                             \
      float v = ACC[g] + bias[cofr + g];                                        \
      if (RELU) v = fmaxf(v, 0.f);                                              \
      pk[g] = f2bf(v);                                                          \
    }                                                                           \
    *(u16x4*)(out + (rowbase + wpxj) * Cout + cofr) = pk;                       \
  }
  EPI(acc00, 0, 0) EPI(acc01, 0, 1) EPI(acc10, 1, 0) EPI(acc11, 1, 1)
#undef EPI
}

// ---------------------------------------------------------------------------
// seg-norm stats: per (b, class, channel) sums via atomics. NHWC bf16 input.
// ---------------------------------------------------------------------------
__global__ __launch_bounds__(256) void sn_sum_k(
    const ushort* __restrict__ x, const int* __restrict__ seg,
    float* __restrict__ Ssum, float* __restrict__ Qsum, int C, int logW, int nsl) {
  const int W = 1 << logW, sh = logW - 6;
  const int b = blockIdx.x / nsl, sl = blockIdx.x % nsl;
  const int PPT = 256 / C;
  const int c = threadIdx.x % C;
  const int sub = threadIdx.x / C;
  const int rows = W / nsl;
  const int p0 = sl * rows * W;
  const int np = rows * W;
  const ushort* xp = x + ((size_t)b << (2 * logW)) * C + (size_t)p0 * C;
  const int* segb = seg + (b << 12);
  float S[8] = {0, 0, 0, 0, 0, 0, 0, 0};
  float Q[8] = {0, 0, 0, 0, 0, 0, 0, 0};
  for (int k = sub; k < np; k += PPT) {
    const int p = p0 + k;
    const int cls = segb[(((p >> logW) >> sh) << 6) + ((p & (W - 1)) >> sh)];
    const uint u = xp[(size_t)k * C + c];
    const float v = __builtin_bit_cast(float, u << 16);
#pragma unroll
    for (int t = 0; t < 8; ++t) {
      const bool m = (cls == t);
      S[t] += m ? v : 0.f;
      Q[t] += m ? v * v : 0.f;
    }
  }
#pragma unroll
  for (int t = 0; t < 8; ++t) {
    atomicAdd(&Ssum[((b << 3) + t) * C + c], S[t]);
    atomicAdd(&Qsum[((b << 3) + t) * C + c], Q[t]);
  }
}

__global__ void sn_fin_k(const float* __restrict__ Ssum, const float* __restrict__ Qsum,
                         float* __restrict__ RS, float* __restrict__ KK, int C, float invN) {
  const int tid = threadIdx.x;
  const int b = tid / C, c = tid % C;
  float K = 0.f;
#pragma unroll
  for (int t = 0; t < 8; ++t) {
    const float s = Ssum[((b << 3) + t) * C + c];
    const float q = Qsum[((b << 3) + t) * C + c];
    const float mu = s * invN;
    const float var = q * invN - mu * mu;
    const float r = rsqrtf(var + 1e-5f);
    RS[((b << 3) + t) * C + c] = r;
    K += mu * r;
  }
  KK[b * C + c] = K;
}

// ---------------------------------------------------------------------------
// fused seg-norm apply + bilinear 2x upsample. src NHWC bf16 full (Ws x Ws),
// writes band rows [out_row0, out_row0+out_rows) at 2Ws. 8 channels/thread.
// ---------------------------------------------------------------------------
__global__ __launch_bounds__(256) void up2norm_k(
    const ushort* __restrict__ src, const int* __restrict__ seg,
    const float* __restrict__ RS, const float* __restrict__ KK,
    ushort* __restrict__ out, int C, int logWs, int out_row0, int out_rows) {
  const int Ws = 1 << logWs, W2 = Ws << 1, sh = logWs - 6;
  const int cpb = C >> 3;
  int i = blockIdx.x * 256 + threadIdx.x;
  const int total = 4 * out_rows * W2 * cpb;
  if (i >= total) return;
  const int cc = (i % cpb) * 8; i /= cpb;
  const int ow = i % W2; i /= W2;
  const int r = i % out_rows;
  const int b = i / out_rows;
  const int oh = out_row0 + r;

  int hl = (oh - 1) >> 1;
  const float hf = (oh & 1) ? 0.25f : 0.75f;
  const int hh = min(hl + 1, Ws - 1);
  hl = max(hl, 0);
  int wl = (ow - 1) >> 1;
  const float wfc = (ow & 1) ? 0.25f : 0.75f;
  const int wh = min(wl + 1, Ws - 1);
  wl = max(wl, 0);

  const size_t pl = (size_t)b << (2 * logWs);
  const u32x4 xll = *(const u32x4*)(src + ((pl + hl * Ws + wl) * C + cc));
  const u32x4 xlh = *(const u32x4*)(src + ((pl + hl * Ws + wh) * C + cc));
  const u32x4 xhl = *(const u32x4*)(src + ((pl + hh * Ws + wl) * C + cc));
  const u32x4 xhh = *(const u32x4*)(src + ((pl + hh * Ws + wh) * C + cc));
  const int* segb = seg + (b << 12);
  const int cll = segb[((hl >> sh) << 6) + (wl >> sh)];
  const int clh = segb[((hl >> sh) << 6) + (wh >> sh)];
  const int chl = segb[((hh >> sh) << 6) + (wl >> sh)];
  const int chh = segb[((hh >> sh) << 6) + (wh >> sh)];
  const float* rll = RS + ((b << 3) + cll) * C + cc;
  const float* rlh = RS + ((b << 3) + clh) * C + cc;
  const float* rhl = RS + ((b << 3) + chl) * C + cc;
  const float* rhh = RS + ((b << 3) + chh) * C + cc;
  const float* kk = KK + b * C + cc;

  u32x4 res;
#pragma unroll
  for (int q = 0; q < 4; ++q) {
    const int c0 = 2 * q, c1 = 2 * q + 1;
    const float na0 = bf_lo(xll[q]) * rll[c0], nb0 = bf_lo(xlh[q]) * rlh[c0];
    const float nc0 = bf_lo(xhl[q]) * rhl[c0], nd0 = bf_lo(xhh[q]) * rhh[c0];
    const float na1 = bf_hi(xll[q]) * rll[c1], nb1 = bf_hi(xlh[q]) * rlh[c1];
    const float nc1 = bf_hi(xhl[q]) * rhl[c1], nd1 = bf_hi(xhh[q]) * rhh[c1];
    const float t0 = na0 + wfc * (nb0 - na0), bo0 = nc0 + wfc * (nd0 - nc0);
    const float t1 = na1 + wfc * (nb1 - na1), bo1 = nc1 + wfc * (nd1 - nc1);
    const float o0 = t0 + hf * (bo0 - t0) - kk[c0];
    const float o1 = t1 + hf * (bo1 - t1) - kk[c1];
    res[q] = (uint)f2bf(o0) | ((uint)f2bf(o1) << 16);
  }
  *(u32x4*)(out + (((size_t)(b * out_rows + r)) * W2 + ow) * C + cc) = res;
}

// ---------------------------------------------------------------------------
// final conv 64->3, direct f32, NHWC bf16 band in -> NCHW f32 d_out.
// ---------------------------------------------------------------------------
__global__ __launch_bounds__(256) void convf_k(
    const ushort* __restrict__ in, const float* __restrict__ wf,
    const float* __restrict__ bf, float* __restrict__ out,
    int in_row0, int in_rows, int out_row0, int out_rows) {
  __shared__ float wsm[1728];
  for (int k = threadIdx.x; k < 1728; k += 256) wsm[k] = wf[k];
  __syncthreads();
  int i = blockIdx.x * 256 + threadIdx.x;
  const int total = 4 * out_rows * 512;
  if (i >= total) return;
  const int w = i % 512; i /= 512;
  const int r = i % out_rows;
  const int b = i / out_rows;
  const int h = out_row0 + r;
  const int hrow[3] = {h == 0 ? 1 : h - 1, h, h == 511 ? 510 : h + 1};
  const int wcol[3] = {w == 0 ? 1 : w - 1, w, w == 511 ? 510 : w + 1};
  float a0 = bf[0], a1 = bf[1], a2 = bf[2];
  for (int rr = 0; rr < 3; ++rr)
    for (int ss = 0; ss < 3; ++ss) {
      const int tap = rr * 3 + ss;
      const ushort* p = in + (((size_t)(b * in_rows + (hrow[rr] - in_row0))) * 512 + wcol[ss]) * 64;
#pragma unroll
      for (int cq = 0; cq < 8; ++cq) {
        const u32x4 xv = *(const u32x4*)(p + cq * 8);
#pragma unroll
        for (int q = 0; q < 4; ++q) {
          const float vlo = bf_lo(xv[q]), vhi = bf_hi(xv[q]);
          const int ci = cq * 8 + 2 * q;
          a0 += vlo * wsm[(ci)*9 + tap] + vhi * wsm[(ci + 1) * 9 + tap];
          a1 += vlo * wsm[(64 + ci) * 9 + tap] + vhi * wsm[(64 + ci + 1) * 9 + tap];
          a2 += vlo * wsm[(128 + ci) * 9 + tap] + vhi * wsm[(128 + ci + 1) * 9 + tap];
        }
      }
    }
  const size_t o = ((size_t)h << 9) + w;
  out[((size_t)(b * 3 + 0) << 18) + o] = a0;
  out[((size_t)(b * 3 + 1) << 18) + o] = a1;
  out[((size_t)(b * 3 + 2) << 18) + o] = a2;
}

// weights [Co][Ci][3][3] f32 -> [9][Co][Ci] bf16
__global__ __launch_bounds__(256) void packw_k(const float* __restrict__ w,
                                               ushort* __restrict__ wp, int Co, int Ci) {
  const int i = blockIdx.x * 256 + threadIdx.x;
  const int tot = Co * Ci * 9;
  if (i >= tot) return;
  const int CoCi = Co * Ci;
  const int t = i / CoCi, rem = i % CoCi;
  const int co = rem / Ci, ci = rem % Ci;
  wp[i] = f2bf(w[((size_t)(co * Ci + ci)) * 9 + t]);
}

// x f32 NCHW (4,512,64,64) -> bf16 NHWC via LDS transpose (32c x 64p tiles)
__global__ __launch_bounds__(256) void cvt_x_k(const float* __restrict__ x,
                                               ushort* __restrict__ xn) {
  __shared__ float tile[32][65];
  const int p0 = blockIdx.x * 64, c0 = blockIdx.y * 32, b = blockIdx.z;
  for (int k = threadIdx.x; k < 2048; k += 256) {
    const int ci = k >> 6, pj = k & 63;
    tile[ci][pj] = x[(((size_t)(b * 512 + c0 + ci)) << 12) + p0 + pj];
  }
  __syncthreads();
  for (int k = threadIdx.x; k < 2048; k += 256) {
    const int ci = k & 31, pj = k >> 5;
    xn[((((size_t)b << 12) + p0 + pj)) * 512 + c0 + ci] = f2bf(tile[ci][pj]);
  }
}

// ---------------------------------------------------------------------------
extern "C" void kernel_launch(void* const* d_in, const int* in_sizes, int n_in,
                              void* d_out, int out_size, void* d_ws, size_t ws_size,
                              hipStream_t stream) {
  const float* x = (const float*)d_in[0];
  const int* seg = (const int*)d_in[1];
  const float *w1 = (const float*)d_in[2], *b1 = (const float*)d_in[3];
  const float *w2 = (const float*)d_in[4], *b2 = (const float*)d_in[5];
  const float *w3 = (const float*)d_in[6], *b3 = (const float*)d_in[7];
  const float *w4 = (const float*)d_in[8], *b4 = (const float*)d_in[9];
  const float *w5 = (const float*)d_in[10], *b5 = (const float*)d_in[11];
  const float *w6 = (const float*)d_in[12], *b6 = (const float*)d_in[13];
  const float *w7 = (const float*)d_in[14], *b7 = (const float*)d_in[15];
  const float *w8 = (const float*)d_in[16], *b8 = (const float*)d_in[17];
  const float *wf = (const float*)d_in[18], *bf = (const float*)d_in[19];
  float* outp = (float*)d_out;

  char* wsb = (char*)d_ws;
  const size_t MB = 1048576;
  ushort* w1p = (ushort*)(wsb + 0);
  ushort* w2p = (ushort*)(wsb + 2359296);
  ushort* w3p = (ushort*)(wsb + 3538944);
  ushort* w4p = (ushort*)(wsb + 4718592);
  ushort* w5p = (ushort*)(wsb + 5898240);
  ushort* w6p = (ushort*)(wsb + 6488064);
  ushort* w7p = (ushort*)(wsb + 6782976);
  ushort* w8p = (ushort*)(wsb + 6930432);
  float* Ssum = (float*)(wsb + 8388608);
  float* Qsum = (float*)(wsb + 8421376);
  float* RS = (float*)(wsb + 8454144);
  float* KK = (float*)(wsb + 8486912);
  ushort* XN = (ushort*)(wsb + 16 * MB);  // (4,64,64,512)   16MB
  ushort* A1 = (ushort*)(wsb + 32 * MB);  // (4,64,64,256)    8MB
  ushort* U1 = (ushort*)(wsb + 48 * MB);  // (4,128,128,256) 32MB
  ushort* C2 = (ushort*)(wsb + 80 * MB);  // 32MB
  ushort* C3 = (ushort*)(wsb + 16 * MB);  // 32MB (XN/A1 dead)
  ushort* C4 = (ushort*)(wsb + 48 * MB);  // 32MB (U1 dead)
  ushort* C5 = (ushort*)(wsb + 80 * MB);  // (4,128,128,128) 16MB (C2 dead)
  ushort* U6 = (ushort*)(wsb + 16 * MB);  // band <=68 rows @256 C=128: 17MB
  ushort* C6 = (ushort*)(wsb + 33 * MB);  // band <=66 rows: 16.5MB
  ushort* C7 = (ushort*)(wsb + 96 * MB);  // (4,256,256,64)  32MB
  ushort* U8 = (ushort*)(wsb + 16 * MB);  // band <=68 rows @512 C=64: 17MB
  ushort* C8 = (ushort*)(wsb + 33 * MB);  // band <=66 rows: 16.5MB

  auto cdiv = [](int a, int b) { return (a + b - 1) / b; };

  // weight packs + input conversion
  cvt_x_k<<<dim3(64, 16, 4), 256, 0, stream>>>(x, XN);
  packw_k<<<cdiv(1179648, 256), 256, 0, stream>>>(w1, w1p, 256, 512);
  packw_k<<<cdiv(589824, 256), 256, 0, stream>>>(w2, w2p, 256, 256);
  packw_k<<<cdiv(589824, 256), 256, 0, stream>>>(w3, w3p, 256, 256);
  packw_k<<<cdiv(589824, 256), 256, 0, stream>>>(w4, w4p, 256, 256);
  packw_k<<<cdiv(294912, 256), 256, 0, stream>>>(w5, w5p, 128, 256);
  packw_k<<<cdiv(147456, 256), 256, 0, stream>>>(w6, w6p, 128, 128);
  packw_k<<<cdiv(73728, 256), 256, 0, stream>>>(w7, w7p, 64, 128);
  packw_k<<<cdiv(36864, 256), 256, 0, stream>>>(w8, w8p, 64, 64);

  // ---- @64 ----
  conv_mfma_k<1><<<dim3(1, 64, 16), 256, 0, stream>>>(XN, w1p, b1, A1, 512, 256, 64, 64, 0, 64, 0, 0, 64);
  hipMemsetAsync(Ssum, 0, 65536, stream);
  sn_sum_k<<<4 * 32, 256, 0, stream>>>(A1, seg, Ssum, Qsum, 256, 6, 32);
  sn_fin_k<<<1, 1024, 0, stream>>>(Ssum, Qsum, RS, KK, 256, 1.f / 4096.f);
  up2norm_k<<<cdiv(4 * 128 * 128 * 32, 256), 256, 0, stream>>>(A1, seg, RS, KK, U1, 256, 6, 0, 128);

  // ---- @128 ----
  conv_mfma_k<1><<<dim3(2, 128, 16), 256, 0, stream>>>(U1, w2p, b2, C2, 256, 256, 128, 128, 0, 128, 0, 0, 128);
  conv_mfma_k<1><<<dim3(2, 128, 16), 256, 0, stream>>>(C2, w3p, b3, C3, 256, 256, 128, 128, 0, 128, 0, 0, 128);
  conv_mfma_k<1><<<dim3(2, 128, 16), 256, 0, stream>>>(C3, w4p, b4, C4, 256, 256, 128, 128, 0, 128, 0, 0, 128);
  conv_mfma_k<1><<<dim3(2, 128, 8), 256, 0, stream>>>(C4, w5p, b5, C5, 256, 128, 128, 128, 0, 128, 0, 0, 128);
  hipMemsetAsync(Ssum, 0, 65536, stream);
  sn_sum_k<<<4 * 64, 256, 0, stream>>>(C5, seg, Ssum, Qsum, 128, 7, 64);
  sn_fin_k<<<1, 512, 0, stream>>>(Ssum, Qsum, RS, KK, 128, 1.f / 16384.f);

  // ---- @256, banded: up2norm -> conv6 -> conv7 ----
  for (int kb = 0; kb < 4; ++kb) {
    const int r0 = kb * 64;
    const int Rlo = max(r0 - 1, 0), Rhi = min(r0 + 64, 255);
    const int rows6 = Rhi - Rlo + 1;
    const int Ulo = max(Rlo - 1, 0), Uhi = min(Rhi + 1, 255);
    const int rowsU = Uhi - Ulo + 1;
    up2norm_k<<<cdiv(4 * rowsU * 256 * 16, 256), 256, 0, stream>>>(C5, seg, RS, KK, U6, 128, 7, Ulo, rowsU);
    conv_mfma_k<1><<<dim3(4, rows6, 8), 256, 0, stream>>>(U6, w6p, b6, C6, 128, 128, 256, 256, Ulo, rowsU, Rlo, Rlo, rows6);
    conv_mfma_k<1><<<dim3(4, 64, 4), 256, 0, stream>>>(C6, w7p, b7, C7, 128, 64, 256, 256, Rlo, rows6, r0, 0, 256);
  }
  hipMemsetAsync(Ssum, 0, 65536, stream);
  sn_sum_k<<<4 * 128, 256, 0, stream>>>(C7, seg, Ssum, Qsum, 64, 8, 128);
  sn_fin_k<<<1, 256, 0, stream>>>(Ssum, Qsum, RS, KK, 64, 1.f / 65536.f);

  // ---- @512, banded: up2norm -> conv8 -> convf ----
  for (int kb = 0; kb < 8; ++kb) {
    const int r0 = kb * 64;
    const int Rlo = max(r0 - 1, 0), Rhi = min(r0 + 64, 511);
    const int rows8 = Rhi - Rlo + 1;
    const int Ulo = max(Rlo - 1, 0), Uhi = min(Rhi + 1, 511);
    const int rowsU = Uhi - Ulo + 1;
    up2norm_k<<<cdiv(4 * rowsU * 512 * 8, 256), 256, 0, stream>>>(C7, seg, RS, KK, U8, 64, 8, Ulo, rowsU);
    conv_mfma_k<1><<<dim3(8, rows8, 4), 256, 0, stream>>>(U8, w8p, b8, C8, 64, 64, 512, 512, Ulo, rowsU, Rlo, Rlo, rows8);
    convf_k<<<cdiv(4 * 64 * 512, 256), 256, 0, stream>>>(C8, wf, bf, outp, Rlo, rows8, r0, 64);
  }
}

// Round 4
// 1576.705 us; speedup vs baseline: 9.2793x; 1.7047x over previous
//
#include <hip/hip_runtime.h>

typedef unsigned int uint;
typedef unsigned short ushort;
typedef __bf16 bf16x8 __attribute__((ext_vector_type(8)));
typedef float f32x4 __attribute__((ext_vector_type(4)));
typedef uint u32x4 __attribute__((ext_vector_type(4)));
typedef ushort u16x4 __attribute__((ext_vector_type(4)));

__device__ __forceinline__ float bf_lo(uint u) { return __builtin_bit_cast(float, u << 16); }
__device__ __forceinline__ float bf_hi(uint u) { return __builtin_bit_cast(float, u & 0xFFFF0000u); }
__device__ __forceinline__ ushort f2bf(float f) {
  uint u = __builtin_bit_cast(uint, f);
  return (ushort)((u + 0x7FFFu + ((u >> 16) & 1u)) >> 16);
}

// ---------------------------------------------------------------------------
// MFMA implicit-GEMM 3x3 conv, reflect-pad-1, bias, relu. NHWC bf16 bands.
// Weights prepacked [9][Co/16][Ci/32][lane64][8] bf16 (MFMA-native, coalesced).
// Block: 256 thr = 4 waves. Tile: 64co x 64px x 4 rows. Wave: 64co x 16px.
// K-loop (NCH chunks of 32 ci): per chunk 9 taps x 4 rows x 4 MFMA = 144/wave.
// Input band [6 rows][66 px][32 ci] in LDS, XOR-swizzled, double-buffered.
// ---------------------------------------------------------------------------
template<int NCH, int RELU>
__global__ __launch_bounds__(256) void conv_mfma_k(
    const ushort* __restrict__ in, const ushort* __restrict__ wp,
    const float* __restrict__ bias, ushort* __restrict__ out,
    int Cout, int H, int W,
    int in_row0, int in_rows, int out_row0, int out_rows,
    int ob_row0, int ob_rows) {
  constexpr int Cin = NCH * 32;
  __shared__ ushort lds[2][14336];  // 2 x 1792 slots x 16B = 2 x 28KB
  const int tid = threadIdx.x;
  const int lane = tid & 63;
  const int wv = tid >> 6;
  const int wx0 = blockIdx.x * 64;
  const int nCoB = Cout >> 6;
  const int cob = (blockIdx.z % nCoB) * 64;
  const int b = blockIdx.z / nCoB;
  const int h0 = out_row0 + blockIdx.y * 4;
  const int nCb = Cout >> 4;
  const int cb0 = cob >> 4;

  // band rows: logical h0-1 .. h0+4 with image reflect, clamped to band
  int hs[6];
#pragma unroll
  for (int r = 0; r < 6; ++r) {
    int hh = h0 - 1 + r;
    if (hh < 0) hh = 1;
    if (hh >= H) hh = 2 * (H - 1) - hh;
    hh = min(max(hh, in_row0), in_row0 + in_rows - 1);
    hs[r] = hh - in_row0;
  }

  // staging: slot t = (r*66+px)*4 + kg'  (1792 slots incl. pad tail)
  const ushort* gsrc[7];
  uint lof[7];
#pragma unroll
  for (int p = 0; p < 7; ++p) {
    const int t = p * 256 + tid;
    const int px_g = t >> 2, kgs = t & 3;
    int rr = px_g / 66;
    const int px = (rr > 5) ? (px_g - 6 * 66) : (px_g - rr * 66);
    if (rr > 5) rr = 5;
    const int kg = kgs ^ ((px >> 1) & 3);  // inverse swizzle on global source
    int wsrc = wx0 + px - 1;
    wsrc = (wsrc < 0) ? 1 : (wsrc >= W ? W - 2 : wsrc);
    gsrc[p] = in + ((size_t)(b * in_rows + hs[rr]) * W + wsrc) * Cin + kg * 8;
    lof[p] = (uint)((p * 256 + wv * 64) * 8);  // wave-uniform base (ushorts)
  }

  const int bpx = wv * 16 + (lane & 15);   // this wave's px (column) index
  const int bkg = lane >> 4;

  f32x4 acc[4][4] = {};

  auto stage = [&](int buf, int ci0) {
#pragma unroll
    for (int p = 0; p < 7; ++p) {
      __builtin_amdgcn_global_load_lds(
          (const __attribute__((address_space(1))) void*)(gsrc[p] + ci0),
          (__attribute__((address_space(3))) void*)(&lds[buf][lof[p]]), 16, 0, 0);
    }
  };
  auto compute = [&](int buf, int kc) {
    const ushort* lb = &lds[buf][0];
#pragma unroll
    for (int t9 = 0; t9 < 9; ++t9) {
      const int dr = t9 / 3, s = t9 - dr * 3;
      bf16x8 afr[4];
#pragma unroll
      for (int ii = 0; ii < 4; ++ii) {
        const int off = (((t9 * nCb + cb0 + ii) * NCH + kc) << 9) + (lane << 3);
        afr[ii] = __builtin_bit_cast(bf16x8, *(const u32x4*)(wp + off));
      }
      const int px = bpx + s;
      const int swz = bkg ^ ((px >> 1) & 3);
#pragma unroll
      for (int rr = 0; rr < 4; ++rr) {
        const int sl = (((rr + dr) * 66 + px) << 2) + swz;
        const bf16x8 bfrag = __builtin_bit_cast(bf16x8, *(const u32x4*)(lb + sl * 8));
#pragma unroll
        for (int ii = 0; ii < 4; ++ii)
          acc[rr][ii] = __builtin_amdgcn_mfma_f32_16x16x32_bf16(afr[ii], bfrag, acc[rr][ii], 0, 0, 0);
      }
    }
  };

  stage(0, 0);
  asm volatile("s_waitcnt vmcnt(0)" ::: "memory");
  __syncthreads();
#pragma unroll 1
  for (int c = 0; c < NCH; ++c) {
    if (c + 1 < NCH) stage((c + 1) & 1, (c + 1) * 32);
    compute(c & 1, c);
    asm volatile("s_waitcnt vmcnt(0)" ::: "memory");
    __syncthreads();
  }

  // epilogue: D col=lane&15 (px), row=(lane>>4)*4+reg (co within 16)
  const int cofr = cob + (lane >> 4) * 4;
  const int pxo = wx0 + bpx;
#pragma unroll
  for (int rr = 0; rr < 4; ++rr) {
    const int h = h0 + rr;
    if (h >= out_row0 + out_rows) break;
    const size_t base = ((size_t)(b * ob_rows + (h - ob_row0)) * W + pxo) * Cout;
#pragma unroll
    for (int ii = 0; ii < 4; ++ii) {
      u16x4 pk;
#pragma unroll
      for (int g = 0; g < 4; ++g) {
        float v = acc[rr][ii][g] + bias[cofr + ii * 16 + g];
        if (RELU) v = fmaxf(v, 0.f);
        pk[g] = f2bf(v);
      }
      *(u16x4*)(out + base + cofr + ii * 16) = pk;
    }
  }
}

// ---------------------------------------------------------------------------
// seg-norm stats: per (b, class, channel) sums via atomics. NHWC bf16 input.
// ---------------------------------------------------------------------------
__global__ __launch_bounds__(256) void sn_sum_k(
    const ushort* __restrict__ x, const int* __restrict__ seg,
    float* __restrict__ Ssum, float* __restrict__ Qsum, int C, int logW, int nsl) {
  const int W = 1 << logW, sh = logW - 6;
  const int b = blockIdx.x / nsl, sl = blockIdx.x % nsl;
  const int PPT = 256 / C;
  const int c = threadIdx.x % C;
  const int sub = threadIdx.x / C;
  const int rows = W / nsl;
  const int p0 = sl * rows * W;
  const int np = rows * W;
  const ushort* xp = x + ((size_t)b << (2 * logW)) * C + (size_t)p0 * C;
  const int* segb = seg + (b << 12);
  float S[8] = {0, 0, 0, 0, 0, 0, 0, 0};
  float Q[8] = {0, 0, 0, 0, 0, 0, 0, 0};
  for (int k = sub; k < np; k += PPT) {
    const int p = p0 + k;
    const int cls = segb[(((p >> logW) >> sh) << 6) + ((p & (W - 1)) >> sh)];
    const uint u = xp[(size_t)k * C + c];
    const float v = __builtin_bit_cast(float, u << 16);
#pragma unroll
    for (int t = 0; t < 8; ++t) {
      const bool m = (cls == t);
      S[t] += m ? v : 0.f;
      Q[t] += m ? v * v : 0.f;
    }
  }
#pragma unroll
  for (int t = 0; t < 8; ++t) {
    atomicAdd(&Ssum[((b << 3) + t) * C + c], S[t]);
    atomicAdd(&Qsum[((b << 3) + t) * C + c], Q[t]);
  }
}

__global__ void sn_fin_k(const float* __restrict__ Ssum, const float* __restrict__ Qsum,
                         float* __restrict__ RS, float* __restrict__ KK, int C, float invN) {
  const int tid = threadIdx.x;
  const int b = tid / C, c = tid % C;
  float K = 0.f;
#pragma unroll
  for (int t = 0; t < 8; ++t) {
    const float s = Ssum[((b << 3) + t) * C + c];
    const float q = Qsum[((b << 3) + t) * C + c];
    const float mu = s * invN;
    const float var = q * invN - mu * mu;
    const float r = rsqrtf(var + 1e-5f);
    RS[((b << 3) + t) * C + c] = r;
    K += mu * r;
  }
  KK[b * C + c] = K;
}

// ---------------------------------------------------------------------------
// fused seg-norm apply + bilinear 2x upsample. src NHWC bf16 full (Ws x Ws),
// writes band rows [out_row0, out_row0+out_rows) at 2Ws. 8 channels/thread.
// ---------------------------------------------------------------------------
__global__ __launch_bounds__(256) void up2norm_k(
    const ushort* __restrict__ src, const int* __restrict__ seg,
    const float* __restrict__ RS, const float* __restrict__ KK,
    ushort* __restrict__ out, int C, int logWs, int out_row0, int out_rows) {
  const int Ws = 1 << logWs, W2 = Ws << 1, sh = logWs - 6;
  const int cpb = C >> 3;
  int i = blockIdx.x * 256 + threadIdx.x;
  const int total = 4 * out_rows * W2 * cpb;
  if (i >= total) return;
  const int cc = (i % cpb) * 8; i /= cpb;
  const int ow = i % W2; i /= W2;
  const int r = i % out_rows;
  const int b = i / out_rows;
  const int oh = out_row0 + r;

  int hl = (oh - 1) >> 1;
  const float hf = (oh & 1) ? 0.25f : 0.75f;
  const int hh = min(hl + 1, Ws - 1);
  hl = max(hl, 0);
  int wl = (ow - 1) >> 1;
  const float wfc = (ow & 1) ? 0.25f : 0.75f;
  const int wh = min(wl + 1, Ws - 1);
  wl = max(wl, 0);

  const size_t pl = (size_t)b << (2 * logWs);
  const u32x4 xll = *(const u32x4*)(src + ((pl + hl * Ws + wl) * C + cc));
  const u32x4 xlh = *(const u32x4*)(src + ((pl + hl * Ws + wh) * C + cc));
  const u32x4 xhl = *(const u32x4*)(src + ((pl + hh * Ws + wl) * C + cc));
  const u32x4 xhh = *(const u32x4*)(src + ((pl + hh * Ws + wh) * C + cc));
  const int* segb = seg + (b << 12);
  const int cll = segb[((hl >> sh) << 6) + (wl >> sh)];
  const int clh = segb[((hl >> sh) << 6) + (wh >> sh)];
  const int chl = segb[((hh >> sh) << 6) + (wl >> sh)];
  const int chh = segb[((hh >> sh) << 6) + (wh >> sh)];
  const float* rll = RS + ((b << 3) + cll) * C + cc;
  const float* rlh = RS + ((b << 3) + clh) * C + cc;
  const float* rhl = RS + ((b << 3) + chl) * C + cc;
  const float* rhh = RS + ((b << 3) + chh) * C + cc;
  const float* kk = KK + b * C + cc;

  u32x4 res;
#pragma unroll
  for (int q = 0; q < 4; ++q) {
    const int c0 = 2 * q, c1 = 2 * q + 1;
    const float na0 = bf_lo(xll[q]) * rll[c0], nb0 = bf_lo(xlh[q]) * rlh[c0];
    const float nc0 = bf_lo(xhl[q]) * rhl[c0], nd0 = bf_lo(xhh[q]) * rhh[c0];
    const float na1 = bf_hi(xll[q]) * rll[c1], nb1 = bf_hi(xlh[q]) * rlh[c1];
    const float nc1 = bf_hi(xhl[q]) * rhl[c1], nd1 = bf_hi(xhh[q]) * rhh[c1];
    const float t0 = na0 + wfc * (nb0 - na0), bo0 = nc0 + wfc * (nd0 - nc0);
    const float t1 = na1 + wfc * (nb1 - na1), bo1 = nc1 + wfc * (nd1 - nc1);
    const float o0 = t0 + hf * (bo0 - t0) - kk[c0];
    const float o1 = t1 + hf * (bo1 - t1) - kk[c1];
    res[q] = (uint)f2bf(o0) | ((uint)f2bf(o1) << 16);
  }
  *(u32x4*)(out + (((size_t)(b * out_rows + r)) * W2 + ow) * C + cc) = res;
}

// ---------------------------------------------------------------------------
// final conv 64->3, direct f32, NHWC bf16 band in -> NCHW f32 d_out.
// ---------------------------------------------------------------------------
__global__ __launch_bounds__(256) void convf_k(
    const ushort* __restrict__ in, const float* __restrict__ wf,
    const float* __restrict__ bf, float* __restrict__ out,
    int in_row0, int in_rows, int out_row0, int out_rows) {
  __shared__ float wsm[1728];
  for (int k = threadIdx.x; k < 1728; k += 256) wsm[k] = wf[k];
  __syncthreads();
  int i = blockIdx.x * 256 + threadIdx.x;
  const int total = 4 * out_rows * 512;
  if (i >= total) return;
  const int w = i % 512; i /= 512;
  const int r = i % out_rows;
  const int b = i / out_rows;
  const int h = out_row0 + r;
  const int hrow[3] = {h == 0 ? 1 : h - 1, h, h == 511 ? 510 : h + 1};
  const int wcol[3] = {w == 0 ? 1 : w - 1, w, w == 511 ? 510 : w + 1};
  float a0 = bf[0], a1 = bf[1], a2 = bf[2];
  for (int rr = 0; rr < 3; ++rr)
    for (int ss = 0; ss < 3; ++ss) {
      const int tap = rr * 3 + ss;
      const ushort* p = in + (((size_t)(b * in_rows + (hrow[rr] - in_row0))) * 512 + wcol[ss]) * 64;
#pragma unroll
      for (int cq = 0; cq < 8; ++cq) {
        const u32x4 xv = *(const u32x4*)(p + cq * 8);
#pragma unroll
        for (int q = 0; q < 4; ++q) {
          const float vlo = bf_lo(xv[q]), vhi = bf_hi(xv[q]);
          const int ci = cq * 8 + 2 * q;
          a0 += vlo * wsm[(ci)*9 + tap] + vhi * wsm[(ci + 1) * 9 + tap];
          a1 += vlo * wsm[(64 + ci) * 9 + tap] + vhi * wsm[(64 + ci + 1) * 9 + tap];
          a2 += vlo * wsm[(128 + ci) * 9 + tap] + vhi * wsm[(128 + ci + 1) * 9 + tap];
        }
      }
    }
  const size_t o = ((size_t)h << 9) + w;
  out[((size_t)(b * 3 + 0) << 18) + o] = a0;
  out[((size_t)(b * 3 + 1) << 18) + o] = a1;
  out[((size_t)(b * 3 + 2) << 18) + o] = a2;
}

// weights [Co][Ci][3][3] f32 -> [9][Co/16][Ci/32][lane64][8] bf16 (MFMA-native)
__global__ __launch_bounds__(256) void packw_k(const float* __restrict__ w,
                                               ushort* __restrict__ wp, int Co, int Ci) {
  const int i = blockIdx.x * 256 + threadIdx.x;
  const int tot = Co * Ci * 9;
  if (i >= tot) return;
  const int nKc = Ci >> 5;
  const int nCb = Co >> 4;
  const int j = i & 7;
  const int l = (i >> 3) & 63;
  int rest = i >> 9;
  const int kc = rest % nKc; rest /= nKc;
  const int cb = rest % nCb;
  const int t9 = rest / nCb;
  const int co = cb * 16 + (l & 15);
  const int ci = kc * 32 + (l >> 4) * 8 + j;
  wp[i] = f2bf(w[((size_t)(co * Ci + ci)) * 9 + t9]);
}

// x f32 NCHW (4,512,64,64) -> bf16 NHWC via LDS transpose (32c x 64p tiles)
__global__ __launch_bounds__(256) void cvt_x_k(const float* __restrict__ x,
                                               ushort* __restrict__ xn) {
  __shared__ float tile[32][65];
  const int p0 = blockIdx.x * 64, c0 = blockIdx.y * 32, b = blockIdx.z;
  for (int k = threadIdx.x; k < 2048; k += 256) {
    const int ci = k >> 6, pj = k & 63;
    tile[ci][pj] = x[(((size_t)(b * 512 + c0 + ci)) << 12) + p0 + pj];
  }
  __syncthreads();
  for (int k = threadIdx.x; k < 2048; k += 256) {
    const int ci = k & 31, pj = k >> 5;
    xn[((((size_t)b << 12) + p0 + pj)) * 512 + c0 + ci] = f2bf(tile[ci][pj]);
  }
}

// ---------------------------------------------------------------------------
extern "C" void kernel_launch(void* const* d_in, const int* in_sizes, int n_in,
                              void* d_out, int out_size, void* d_ws, size_t ws_size,
                              hipStream_t stream) {
  const float* x = (const float*)d_in[0];
  const int* seg = (const int*)d_in[1];
  const float *w1 = (const float*)d_in[2], *b1 = (const float*)d_in[3];
  const float *w2 = (const float*)d_in[4], *b2 = (const float*)d_in[5];
  const float *w3 = (const float*)d_in[6], *b3 = (const float*)d_in[7];
  const float *w4 = (const float*)d_in[8], *b4 = (const float*)d_in[9];
  const float *w5 = (const float*)d_in[10], *b5 = (const float*)d_in[11];
  const float *w6 = (const float*)d_in[12], *b6 = (const float*)d_in[13];
  const float *w7 = (const float*)d_in[14], *b7 = (const float*)d_in[15];
  const float *w8 = (const float*)d_in[16], *b8 = (const float*)d_in[17];
  const float *wf = (const float*)d_in[18], *bf = (const float*)d_in[19];
  float* outp = (float*)d_out;

  char* wsb = (char*)d_ws;
  const size_t MB = 1048576;
  ushort* w1p = (ushort*)(wsb + 0);
  ushort* w2p = (ushort*)(wsb + 2359296);
  ushort* w3p = (ushort*)(wsb + 3538944);
  ushort* w4p = (ushort*)(wsb + 4718592);
  ushort* w5p = (ushort*)(wsb + 5898240);
  ushort* w6p = (ushort*)(wsb + 6488064);
  ushort* w7p = (ushort*)(wsb + 6782976);
  ushort* w8p = (ushort*)(wsb + 6930432);
  float* Ssum = (float*)(wsb + 8388608);
  float* Qsum = (float*)(wsb + 8421376);
  float* RS = (float*)(wsb + 8454144);
  float* KK = (float*)(wsb + 8486912);
  ushort* XN = (ushort*)(wsb + 16 * MB);  // (4,64,64,512)   16MB
  ushort* A1 = (ushort*)(wsb + 32 * MB);  // (4,64,64,256)    8MB
  ushort* U1 = (ushort*)(wsb + 48 * MB);  // (4,128,128,256) 32MB
  ushort* C2 = (ushort*)(wsb + 80 * MB);  // 32MB
  ushort* C3 = (ushort*)(wsb + 16 * MB);  // 32MB (XN/A1 dead)
  ushort* C4 = (ushort*)(wsb + 48 * MB);  // 32MB (U1 dead)
  ushort* C5 = (ushort*)(wsb + 80 * MB);  // (4,128,128,128) 16MB (C2 dead)
  ushort* U6 = (ushort*)(wsb + 16 * MB);  // band <=68 rows @256 C=128: 17MB
  ushort* C6 = (ushort*)(wsb + 33 * MB);  // band <=66 rows: 16.5MB
  ushort* C7 = (ushort*)(wsb + 96 * MB);  // (4,256,256,64)  32MB
  ushort* U8 = (ushort*)(wsb + 16 * MB);  // band <=68 rows @512 C=64: 17MB
  ushort* C8 = (ushort*)(wsb + 33 * MB);  // band <=66 rows: 16.5MB

  auto cdiv = [](int a, int b) { return (a + b - 1) / b; };

  // weight packs + input conversion
  cvt_x_k<<<dim3(64, 16, 4), 256, 0, stream>>>(x, XN);
  packw_k<<<cdiv(1179648, 256), 256, 0, stream>>>(w1, w1p, 256, 512);
  packw_k<<<cdiv(589824, 256), 256, 0, stream>>>(w2, w2p, 256, 256);
  packw_k<<<cdiv(589824, 256), 256, 0, stream>>>(w3, w3p, 256, 256);
  packw_k<<<cdiv(589824, 256), 256, 0, stream>>>(w4, w4p, 256, 256);
  packw_k<<<cdiv(294912, 256), 256, 0, stream>>>(w5, w5p, 128, 256);
  packw_k<<<cdiv(147456, 256), 256, 0, stream>>>(w6, w6p, 128, 128);
  packw_k<<<cdiv(73728, 256), 256, 0, stream>>>(w7, w7p, 64, 128);
  packw_k<<<cdiv(36864, 256), 256, 0, stream>>>(w8, w8p, 64, 64);

  // ---- @64 ----
  conv_mfma_k<16, 1><<<dim3(1, 16, 16), 256, 0, stream>>>(
      XN, w1p, b1, A1, 256, 64, 64, 0, 64, 0, 64, 0, 64);
  hipMemsetAsync(Ssum, 0, 65536, stream);
  sn_sum_k<<<4 * 32, 256, 0, stream>>>(A1, seg, Ssum, Qsum, 256, 6, 32);
  sn_fin_k<<<1, 1024, 0, stream>>>(Ssum, Qsum, RS, KK, 256, 1.f / 4096.f);
  up2norm_k<<<cdiv(4 * 128 * 128 * 32, 256), 256, 0, stream>>>(A1, seg, RS, KK, U1, 256, 6, 0, 128);

  // ---- @128 ----
  conv_mfma_k<8, 1><<<dim3(2, 32, 16), 256, 0, stream>>>(
      U1, w2p, b2, C2, 256, 128, 128, 0, 128, 0, 128, 0, 128);
  conv_mfma_k<8, 1><<<dim3(2, 32, 16), 256, 0, stream>>>(
      C2, w3p, b3, C3, 256, 128, 128, 0, 128, 0, 128, 0, 128);
  conv_mfma_k<8, 1><<<dim3(2, 32, 16), 256, 0, stream>>>(
      C3, w4p, b4, C4, 256, 128, 128, 0, 128, 0, 128, 0, 128);
  conv_mfma_k<8, 1><<<dim3(2, 32, 8), 256, 0, stream>>>(
      C4, w5p, b5, C5, 128, 128, 128, 0, 128, 0, 128, 0, 128);
  hipMemsetAsync(Ssum, 0, 65536, stream);
  sn_sum_k<<<4 * 64, 256, 0, stream>>>(C5, seg, Ssum, Qsum, 128, 7, 64);
  sn_fin_k<<<1, 512, 0, stream>>>(Ssum, Qsum, RS, KK, 128, 1.f / 16384.f);

  // ---- @256, banded: up2norm -> conv6 -> conv7 ----
  for (int kb = 0; kb < 4; ++kb) {
    const int r0 = kb * 64;
    const int Rlo = max(r0 - 1, 0), Rhi = min(r0 + 64, 255);
    const int rows6 = Rhi - Rlo + 1;
    const int Ulo = max(Rlo - 1, 0), Uhi = min(Rhi + 1, 255);
    const int rowsU = Uhi - Ulo + 1;
    up2norm_k<<<cdiv(4 * rowsU * 256 * 16, 256), 256, 0, stream>>>(C5, seg, RS, KK, U6, 128, 7, Ulo, rowsU);
    conv_mfma_k<4, 1><<<dim3(4, cdiv(rows6, 4), 8), 256, 0, stream>>>(
        U6, w6p, b6, C6, 128, 256, 256, Ulo, rowsU, Rlo, rows6, Rlo, rows6);
    conv_mfma_k<4, 1><<<dim3(4, 16, 4), 256, 0, stream>>>(
        C6, w7p, b7, C7, 64, 256, 256, Rlo, rows6, r0, 64, 0, 256);
  }
  hipMemsetAsync(Ssum, 0, 65536, stream);
  sn_sum_k<<<4 * 128, 256, 0, stream>>>(C7, seg, Ssum, Qsum, 64, 8, 128);
  sn_fin_k<<<1, 256, 0, stream>>>(Ssum, Qsum, RS, KK, 64, 1.f / 65536.f);

  // ---- @512, banded: up2norm -> conv8 -> convf ----
  for (int kb = 0; kb < 8; ++kb) {
    const int r0 = kb * 64;
    const int Rlo = max(r0 - 1, 0), Rhi = min(r0 + 64, 511);
    const int rows8 = Rhi - Rlo + 1;
    const int Ulo = max(Rlo - 1, 0), Uhi = min(Rhi + 1, 511);
    const int rowsU = Uhi - Ulo + 1;
    up2norm_k<<<cdiv(4 * rowsU * 512 * 8, 256), 256, 0, stream>>>(C7, seg, RS, KK, U8, 64, 8, Ulo, rowsU);
    conv_mfma_k<2, 1><<<dim3(8, cdiv(rows8, 4), 4), 256, 0, stream>>>(
        U8, w8p, b8, C8, 64, 512, 512, Ulo, rowsU, Rlo, rows8, Rlo, rows8);
    convf_k<<<cdiv(4 * 64 * 512, 256), 256, 0, stream>>>(C8, wf, bf, outp, Rlo, rows8, r0, 64);
  }
}

// Round 6
// 1228.145 us; speedup vs baseline: 11.9128x; 1.2838x over previous
//
#include <hip/hip_runtime.h>

typedef unsigned int uint;
typedef unsigned short ushort;
typedef __bf16 bf16x8 __attribute__((ext_vector_type(8)));
typedef float f32x4 __attribute__((ext_vector_type(4)));
typedef uint u32x4 __attribute__((ext_vector_type(4)));
typedef ushort u16x4 __attribute__((ext_vector_type(4)));

__device__ __forceinline__ float bf_lo(uint u) { return __builtin_bit_cast(float, u << 16); }
__device__ __forceinline__ float bf_hi(uint u) { return __builtin_bit_cast(float, u & 0xFFFF0000u); }
__device__ __forceinline__ ushort f2bf(float f) {
  uint u = __builtin_bit_cast(uint, f);
  return (ushort)((u + 0x7FFFu + ((u >> 16) & 1u)) >> 16);
}

// ---------------------------------------------------------------------------
// MFMA implicit-GEMM 3x3 conv, reflect-pad-1, bias, relu. NHWC bf16 bands.
// Weights prepacked [9][Co/16][Ci/32][lane64][8] bf16 (MFMA-native, coalesced).
// Block: 256 thr = 4 waves. Tile: 64co x 64px x ROWS rows. Wave: 64co x 16px.
// LDS: [2][(ROWS+2)*66*4 slots * 16B], XOR-swizzled, exactly sized (no pad)
// so 2 buffers = 49.5KB (ROWS=4) -> 3 blocks/CU.
// ---------------------------------------------------------------------------
template<int NCH, int ROWS, int RELU>
__global__ __launch_bounds__(256) void conv_mfma_k(
    const ushort* __restrict__ in, const ushort* __restrict__ wp,
    const float* __restrict__ bias, ushort* __restrict__ out,
    int Cout, int H, int W,
    int in_row0, int in_rows, int out_row0, int out_rows,
    int ob_row0, int ob_rows) {
  constexpr int Cin = NCH * 32;
  constexpr int SLOTS = (ROWS + 2) * 66 * 4;      // 16B slots per buffer
  constexpr int NPASS = (SLOTS + 255) / 256;
  constexpr int LAST = SLOTS - (NPASS - 1) * 256; // active lanes in last pass
  __shared__ ushort lds[2][SLOTS * 8];
  const int tid = threadIdx.x;
  const int lane = tid & 63;
  const int wv = tid >> 6;
  const int wx0 = blockIdx.x * 64;
  const int nCoB = Cout >> 6;
  const int cob = (blockIdx.z % nCoB) * 64;
  const int b = blockIdx.z / nCoB;
  const int h0 = out_row0 + blockIdx.y * ROWS;
  const int nCb = Cout >> 4;
  const int cb0 = cob >> 4;

  // band rows: logical h0-1 .. h0+ROWS with image reflect, clamped to band
  int hs[ROWS + 2];
#pragma unroll
  for (int r = 0; r < ROWS + 2; ++r) {
    int hh = h0 - 1 + r;
    if (hh < 0) hh = 1;
    if (hh >= H) hh = 2 * (H - 1) - hh;
    hh = min(max(hh, in_row0), in_row0 + in_rows - 1);
    hs[r] = hh - in_row0;
  }

  // staging: slot t = (r*66+px)*4 + kg'
  const ushort* gsrc[NPASS];
  uint lof[NPASS];
#pragma unroll
  for (int p = 0; p < NPASS; ++p) {
    const int t = p * 256 + tid;
    const int px_g = t >> 2, kgs = t & 3;
    int rr = px_g / 66;
    int px = px_g - rr * 66;
    if (rr > ROWS + 1) { px = px_g - (ROWS + 2) * 66; rr = ROWS + 1; }
    const int kg = kgs ^ ((px >> 1) & 3);  // inverse swizzle on global source
    int wsrc = wx0 + px - 1;
    wsrc = (wsrc < 0) ? 1 : (wsrc >= W ? W - 2 : wsrc);
    gsrc[p] = in + ((size_t)(b * in_rows + hs[rr]) * W + wsrc) * Cin + kg * 8;
    lof[p] = (uint)((p * 256 + wv * 64) * 8);  // wave-uniform base (ushorts)
  }

  const int bpx = wv * 16 + (lane & 15);
  const int bkg = lane >> 4;

  f32x4 acc[ROWS][4] = {};

  auto stage = [&](int buf, int ci0) {
#pragma unroll
    for (int p = 0; p < NPASS; ++p) {
      if (p + 1 < NPASS || tid < LAST)
        __builtin_amdgcn_global_load_lds(
            (const __attribute__((address_space(1))) void*)(gsrc[p] + ci0),
            (__attribute__((address_space(3))) void*)(&lds[buf][lof[p]]), 16, 0, 0);
    }
  };
  auto compute = [&](int buf, int kc) {
    const ushort* lb = &lds[buf][0];
#pragma unroll
    for (int t9 = 0; t9 < 9; ++t9) {
      const int dr = t9 / 3, s = t9 - dr * 3;
      bf16x8 afr[4];
#pragma unroll
      for (int ii = 0; ii < 4; ++ii) {
        const int off = (((t9 * nCb + cb0 + ii) * NCH + kc) << 9) + (lane << 3);
        afr[ii] = __builtin_bit_cast(bf16x8, *(const u32x4*)(wp + off));
      }
      const int px = bpx + s;
      const int swz = bkg ^ ((px >> 1) & 3);
#pragma unroll
      for (int rr = 0; rr < ROWS; ++rr) {
        const int sl = (((rr + dr) * 66 + px) << 2) + swz;
        const bf16x8 bfrag = __builtin_bit_cast(bf16x8, *(const u32x4*)(lb + sl * 8));
#pragma unroll
        for (int ii = 0; ii < 4; ++ii)
          acc[rr][ii] = __builtin_amdgcn_mfma_f32_16x16x32_bf16(afr[ii], bfrag, acc[rr][ii], 0, 0, 0);
      }
    }
  };

  stage(0, 0);
  asm volatile("s_waitcnt vmcnt(0)" ::: "memory");
  __syncthreads();
#pragma unroll 1
  for (int c = 0; c < NCH; ++c) {
    if (c + 1 < NCH) stage((c + 1) & 1, (c + 1) * 32);
    compute(c & 1, c);
    asm volatile("s_waitcnt vmcnt(0)" ::: "memory");
    __syncthreads();
  }

  // epilogue: D col=lane&15 (px), row=(lane>>4)*4+reg (co within 16)
  const int cofr = cob + (lane >> 4) * 4;
  const int pxo = wx0 + bpx;
#pragma unroll
  for (int rr = 0; rr < ROWS; ++rr) {
    const int h = h0 + rr;
    if (h >= out_row0 + out_rows) break;
    const size_t base = ((size_t)(b * ob_rows + (h - ob_row0)) * W + pxo) * Cout;
#pragma unroll
    for (int ii = 0; ii < 4; ++ii) {
      u16x4 pk;
#pragma unroll
      for (int g = 0; g < 4; ++g) {
        float v = acc[rr][ii][g] + bias[cofr + ii * 16 + g];
        if (RELU) v = fmaxf(v, 0.f);
        pk[g] = f2bf(v);
      }
      *(u16x4*)(out + base + cofr + ii * 16) = pk;
    }
  }
}

// ---------------------------------------------------------------------------
// final conv 64->3 via MFMA with Cout padded to 16 (rows 3..15 zero).
// Same staging as conv_mfma_k (Cin=64, ROWS=4). Output f32 NCHW to d_out.
// ---------------------------------------------------------------------------
__global__ __launch_bounds__(256) void convf_mfma_k(
    const ushort* __restrict__ in, const ushort* __restrict__ wp,
    const float* __restrict__ bias, float* __restrict__ out,
    int in_row0, int in_rows, int out_row0, int out_rows) {
  constexpr int ROWS = 4, NCH = 2, W = 512, H = 512, Cin = 64;
  constexpr int SLOTS = (ROWS + 2) * 66 * 4;
  constexpr int NPASS = (SLOTS + 255) / 256;
  constexpr int LAST = SLOTS - (NPASS - 1) * 256;
  __shared__ ushort lds[2][SLOTS * 8];
  const int tid = threadIdx.x;
  const int lane = tid & 63;
  const int wv = tid >> 6;
  const int wx0 = blockIdx.x * 64;
  const int b = blockIdx.z;
  const int h0 = out_row0 + blockIdx.y * ROWS;

  int hs[ROWS + 2];
#pragma unroll
  for (int r = 0; r < ROWS + 2; ++r) {
    int hh = h0 - 1 + r;
    if (hh < 0) hh = 1;
    if (hh >= H) hh = 2 * (H - 1) - hh;
    hh = min(max(hh, in_row0), in_row0 + in_rows - 1);
    hs[r] = hh - in_row0;
  }
  const ushort* gsrc[NPASS];
  uint lof[NPASS];
#pragma unroll
  for (int p = 0; p < NPASS; ++p) {
    const int t = p * 256 + tid;
    const int px_g = t >> 2, kgs = t & 3;
    int rr = px_g / 66;
    int px = px_g - rr * 66;
    if (rr > ROWS + 1) { px = px_g - (ROWS + 2) * 66; rr = ROWS + 1; }
    const int kg = kgs ^ ((px >> 1) & 3);
    int wsrc = wx0 + px - 1;
    wsrc = (wsrc < 0) ? 1 : (wsrc >= W ? W - 2 : wsrc);
    gsrc[p] = in + ((size_t)(b * in_rows + hs[rr]) * W + wsrc) * Cin + kg * 8;
    lof[p] = (uint)((p * 256 + wv * 64) * 8);
  }
  const int bpx = wv * 16 + (lane & 15);
  const int bkg = lane >> 4;
  f32x4 acc[ROWS] = {};

  auto stage = [&](int buf, int ci0) {
#pragma unroll
    for (int p = 0; p < NPASS; ++p) {
      if (p + 1 < NPASS || tid < LAST)
        __builtin_amdgcn_global_load_lds(
            (const __attribute__((address_space(1))) void*)(gsrc[p] + ci0),
            (__attribute__((address_space(3))) void*)(&lds[buf][lof[p]]), 16, 0, 0);
    }
  };
  auto compute = [&](int buf, int kc) {
    const ushort* lb = &lds[buf][0];
#pragma unroll
    for (int t9 = 0; t9 < 9; ++t9) {
      const int dr = t9 / 3, s = t9 - dr * 3;
      const int off = (((t9 * NCH) + kc) << 9) + (lane << 3);
      const bf16x8 afr = __builtin_bit_cast(bf16x8, *(const u32x4*)(wp + off));
      const int px = bpx + s;
      const int swz = bkg ^ ((px >> 1) & 3);
#pragma unroll
      for (int rr = 0; rr < ROWS; ++rr) {
        const int sl = (((rr + dr) * 66 + px) << 2) + swz;
        const bf16x8 bfrag = __builtin_bit_cast(bf16x8, *(const u32x4*)(lb + sl * 8));
        acc[rr] = __builtin_amdgcn_mfma_f32_16x16x32_bf16(afr, bfrag, acc[rr], 0, 0, 0);
      }
    }
  };

  stage(0, 0);
  asm volatile("s_waitcnt vmcnt(0)" ::: "memory");
  __syncthreads();
#pragma unroll 1
  for (int c = 0; c < NCH; ++c) {
    if (c + 1 < NCH) stage((c + 1) & 1, (c + 1) * 32);
    compute(c & 1, c);
    asm volatile("s_waitcnt vmcnt(0)" ::: "memory");
    __syncthreads();
  }

  if ((lane >> 4) == 0) {  // co rows 0..3 hold channels 0..2
    const int pxo = wx0 + bpx;
#pragma unroll
    for (int rr = 0; rr < ROWS; ++rr) {
      const int h = h0 + rr;
      if (h >= out_row0 + out_rows) break;
#pragma unroll
      for (int g = 0; g < 3; ++g)
        out[(((size_t)(b * 3 + g)) << 18) + ((size_t)h << 9) + pxo] = acc[rr][g] + bias[g];
    }
  }
}

// ---------------------------------------------------------------------------
// seg-norm stats: per (b, class, channel) sums via atomics. NHWC bf16 input.
// ---------------------------------------------------------------------------
__global__ __launch_bounds__(256) void sn_sum_k(
    const ushort* __restrict__ x, const int* __restrict__ seg,
    float* __restrict__ Ssum, float* __restrict__ Qsum, int C, int logW, int nsl) {
  const int W = 1 << logW, sh = logW - 6;
  const int b = blockIdx.x / nsl, sl = blockIdx.x % nsl;
  const int PPT = 256 / C;
  const int c = threadIdx.x % C;
  const int sub = threadIdx.x / C;
  const int rows = W / nsl;
  const int p0 = sl * rows * W;
  const int np = rows * W;
  const ushort* xp = x + ((size_t)b << (2 * logW)) * C + (size_t)p0 * C;
  const int* segb = seg + (b << 12);
  float S[8] = {0, 0, 0, 0, 0, 0, 0, 0};
  float Q[8] = {0, 0, 0, 0, 0, 0, 0, 0};
  for (int k = sub; k < np; k += PPT) {
    const int p = p0 + k;
    const int cls = segb[(((p >> logW) >> sh) << 6) + ((p & (W - 1)) >> sh)];
    const uint u = xp[(size_t)k * C + c];
    const float v = __builtin_bit_cast(float, u << 16);
#pragma unroll
    for (int t = 0; t < 8; ++t) {
      const bool m = (cls == t);
      S[t] += m ? v : 0.f;
      Q[t] += m ? v * v : 0.f;
    }
  }
#pragma unroll
  for (int t = 0; t < 8; ++t) {
    atomicAdd(&Ssum[((b << 3) + t) * C + c], S[t]);
    atomicAdd(&Qsum[((b << 3) + t) * C + c], Q[t]);
  }
}

__global__ void sn_fin_k(const float* __restrict__ Ssum, const float* __restrict__ Qsum,
                         float* __restrict__ RS, float* __restrict__ KK, int C, float invN) {
  const int tid = threadIdx.x;
  const int b = tid / C, c = tid % C;
  float K = 0.f;
#pragma unroll
  for (int t = 0; t < 8; ++t) {
    const float s = Ssum[((b << 3) + t) * C + c];
    const float q = Qsum[((b << 3) + t) * C + c];
    const float mu = s * invN;
    const float var = q * invN - mu * mu;
    const float r = rsqrtf(var + 1e-5f);
    RS[((b << 3) + t) * C + c] = r;
    K += mu * r;
  }
  KK[b * C + c] = K;
}

// ---------------------------------------------------------------------------
// fused seg-norm apply + bilinear 2x upsample. src NHWC bf16 full (Ws x Ws),
// writes band rows [out_row0, out_row0+out_rows) at 2Ws. 8 channels/thread.
// ---------------------------------------------------------------------------
__global__ __launch_bounds__(256) void up2norm_k(
    const ushort* __restrict__ src, const int* __restrict__ seg,
    const float* __restrict__ RS, const float* __restrict__ KK,
    ushort* __restrict__ out, int C, int logWs, int out_row0, int out_rows) {
  const int Ws = 1 << logWs, W2 = Ws << 1, sh = logWs - 6;
  const int cpb = C >> 3;
  int i = blockIdx.x * 256 + threadIdx.x;
  const int total = 4 * out_rows * W2 * cpb;
  if (i >= total) return;
  const int cc = (i % cpb) * 8; i /= cpb;
  const int ow = i % W2; i /= W2;
  const int r = i % out_rows;
  const int b = i / out_rows;
  const int oh = out_row0 + r;

  int hl = (oh - 1) >> 1;
  const float hf = (oh & 1) ? 0.25f : 0.75f;
  const int hh = min(hl + 1, Ws - 1);
  hl = max(hl, 0);
  int wl = (ow - 1) >> 1;
  const float wfc = (ow & 1) ? 0.25f : 0.75f;
  const int wh = min(wl + 1, Ws - 1);
  wl = max(wl, 0);

  const size_t pl = (size_t)b << (2 * logWs);
  const u32x4 xll = *(const u32x4*)(src + ((pl + hl * Ws + wl) * C + cc));
  const u32x4 xlh = *(const u32x4*)(src + ((pl + hl * Ws + wh) * C + cc));
  const u32x4 xhl = *(const u32x4*)(src + ((pl + hh * Ws + wl) * C + cc));
  const u32x4 xhh = *(const u32x4*)(src + ((pl + hh * Ws + wh) * C + cc));
  const int* segb = seg + (b << 12);
  const int cll = segb[((hl >> sh) << 6) + (wl >> sh)];
  const int clh = segb[((hl >> sh) << 6) + (wh >> sh)];
  const int chl = segb[((hh >> sh) << 6) + (wl >> sh)];
  const int chh = segb[((hh >> sh) << 6) + (wh >> sh)];
  const float* rll = RS + ((b << 3) + cll) * C + cc;
  const float* rlh = RS + ((b << 3) + clh) * C + cc;
  const float* rhl = RS + ((b << 3) + chl) * C + cc;
  const float* rhh = RS + ((b << 3) + chh) * C + cc;
  const float* kk = KK + b * C + cc;

  u32x4 res;
#pragma unroll
  for (int q = 0; q < 4; ++q) {
    const int c0 = 2 * q, c1 = 2 * q + 1;
    const float na0 = bf_lo(xll[q]) * rll[c0], nb0 = bf_lo(xlh[q]) * rlh[c0];
    const float nc0 = bf_lo(xhl[q]) * rhl[c0], nd0 = bf_lo(xhh[q]) * rhh[c0];
    const float na1 = bf_hi(xll[q]) * rll[c1], nb1 = bf_hi(xlh[q]) * rlh[c1];
    const float nc1 = bf_hi(xhl[q]) * rhl[c1], nd1 = bf_hi(xhh[q]) * rhh[c1];
    const float t0 = na0 + wfc * (nb0 - na0), bo0 = nc0 + wfc * (nd0 - nc0);
    const float t1 = na1 + wfc * (nb1 - na1), bo1 = nc1 + wfc * (nd1 - nc1);
    const float o0 = t0 + hf * (bo0 - t0) - kk[c0];
    const float o1 = t1 + hf * (bo1 - t1) - kk[c1];
    res[q] = (uint)f2bf(o0) | ((uint)f2bf(o1) << 16);
  }
  *(u32x4*)(out + (((size_t)(b * out_rows + r)) * W2 + ow) * C + cc) = res;
}

// weights [Co][Ci][3][3] f32 -> [9][Co/16][Ci/32][lane64][8] bf16 (MFMA-native)
__global__ __launch_bounds__(256) void packw_k(const float* __restrict__ w,
                                               ushort* __restrict__ wp, int Co, int Ci) {
  const int i = blockIdx.x * 256 + threadIdx.x;
  const int tot = Co * Ci * 9;
  if (i >= tot) return;
  const int nKc = Ci >> 5;
  const int nCb = Co >> 4;
  const int j = i & 7;
  const int l = (i >> 3) & 63;
  int rest = i >> 9;
  const int kc = rest % nKc; rest /= nKc;
  const int cb = rest % nCb;
  const int t9 = rest / nCb;
  const int co = cb * 16 + (l & 15);
  const int ci = kc * 32 + (l >> 4) * 8 + j;
  wp[i] = f2bf(w[((size_t)(co * Ci + ci)) * 9 + t9]);
}

// wf [3][64][3][3] f32 -> [9][2][lane64][8] bf16 with Co padded 3->16 (zeros)
__global__ __launch_bounds__(256) void packwf_k(const float* __restrict__ w,
                                                ushort* __restrict__ wp) {
  const int i = blockIdx.x * 256 + threadIdx.x;
  if (i >= 9216) return;
  const int j = i & 7;
  const int l = (i >> 3) & 63;
  const int rest = i >> 9;
  const int kc = rest & 1;
  const int t9 = rest >> 1;
  const int co = l & 15;
  const int ci = kc * 32 + (l >> 4) * 8 + j;
  wp[i] = (co < 3) ? f2bf(w[((size_t)(co * 64 + ci)) * 9 + t9]) : (ushort)0;
}

// x f32 NCHW (4,512,64,64) -> bf16 NHWC via LDS transpose (32c x 64p tiles)
__global__ __launch_bounds__(256) void cvt_x_k(const float* __restrict__ x,
                                               ushort* __restrict__ xn) {
  __shared__ float tile[32][65];
  const int p0 = blockIdx.x * 64, c0 = blockIdx.y * 32, b = blockIdx.z;
  for (int k = threadIdx.x; k < 2048; k += 256) {
    const int ci = k >> 6, pj = k & 63;
    tile[ci][pj] = x[(((size_t)(b * 512 + c0 + ci)) << 12) + p0 + pj];
  }
  __syncthreads();
  for (int k = threadIdx.x; k < 2048; k += 256) {
    const int ci = k & 31, pj = k >> 5;
    xn[((((size_t)b << 12) + p0 + pj)) * 512 + c0 + ci] = f2bf(tile[ci][pj]);
  }
}

// ---------------------------------------------------------------------------
extern "C" void kernel_launch(void* const* d_in, const int* in_sizes, int n_in,
                              void* d_out, int out_size, void* d_ws, size_t ws_size,
                              hipStream_t stream) {
  const float* x = (const float*)d_in[0];
  const int* seg = (const int*)d_in[1];
  const float *w1 = (const float*)d_in[2], *b1 = (const float*)d_in[3];
  const float *w2 = (const float*)d_in[4], *b2 = (const float*)d_in[5];
  const float *w3 = (const float*)d_in[6], *b3 = (const float*)d_in[7];
  const float *w4 = (const float*)d_in[8], *b4 = (const float*)d_in[9];
  const float *w5 = (const float*)d_in[10], *b5 = (const float*)d_in[11];
  const float *w6 = (const float*)d_in[12], *b6 = (const float*)d_in[13];
  const float *w7 = (const float*)d_in[14], *b7 = (const float*)d_in[15];
  const float *w8 = (const float*)d_in[16], *b8 = (const float*)d_in[17];
  const float *wf = (const float*)d_in[18], *bf = (const float*)d_in[19];
  float* outp = (float*)d_out;

  char* wsb = (char*)d_ws;
  const size_t MB = 1048576;
  ushort* w1p = (ushort*)(wsb + 0);
  ushort* w2p = (ushort*)(wsb + 2359296);
  ushort* w3p = (ushort*)(wsb + 3538944);
  ushort* w4p = (ushort*)(wsb + 4718592);
  ushort* w5p = (ushort*)(wsb + 5898240);
  ushort* w6p = (ushort*)(wsb + 6488064);
  ushort* w7p = (ushort*)(wsb + 6782976);
  ushort* w8p = (ushort*)(wsb + 6930432);
  ushort* wfp = (ushort*)(wsb + 7004160);
  float* Ssum = (float*)(wsb + 8388608);
  float* Qsum = (float*)(wsb + 8421376);
  float* RS = (float*)(wsb + 8454144);
  float* KK = (float*)(wsb + 8486912);
  // activation arenas (all bf16 NHWC); lifetimes verified disjoint:
  ushort* XN = (ushort*)(wsb + 9 * MB);   // (4,64,64,512)    16MB  [9,25)
  ushort* A1 = (ushort*)(wsb + 25 * MB);  // (4,64,64,256)     8MB  [25,33)
  ushort* U1 = (ushort*)(wsb + 33 * MB);  // (4,128,128,256)  32MB  [33,65)
  ushort* C2 = (ushort*)(wsb + 65 * MB);  // 32MB                   [65,97)
  ushort* C3 = (ushort*)(wsb + 9 * MB);   // 32MB (XN/A1 dead)      [9,41)
  ushort* C4 = (ushort*)(wsb + 41 * MB);  // 32MB (U1/C2 dead)      [41,73)
  ushort* C5 = (ushort*)(wsb + 9 * MB);   // (4,128,128,128)  16MB  [9,25)
  ushort* U6 = (ushort*)(wsb + 25 * MB);  // band <=130 rows 32.5MB [25,58)
  ushort* C6 = (ushort*)(wsb + 58 * MB);  // band <=129 rows 32.3MB [58,91)
  ushort* C7 = (ushort*)(wsb + 91 * MB);  // (4,256,256,64)   32MB  [91,123)
  ushort* U8 = (ushort*)(wsb + 9 * MB);   // band <=132 rows 33MB   [9,43)
  ushort* C8 = (ushort*)(wsb + 43 * MB);  // band <=130 rows 32.5MB [43,76)

  auto cdiv = [](int a, int b) { return (a + b - 1) / b; };

  // weight packs + input conversion
  cvt_x_k<<<dim3(64, 16, 4), 256, 0, stream>>>(x, XN);
  packw_k<<<cdiv(1179648, 256), 256, 0, stream>>>(w1, w1p, 256, 512);
  packw_k<<<cdiv(589824, 256), 256, 0, stream>>>(w2, w2p, 256, 256);
  packw_k<<<cdiv(589824, 256), 256, 0, stream>>>(w3, w3p, 256, 256);
  packw_k<<<cdiv(589824, 256), 256, 0, stream>>>(w4, w4p, 256, 256);
  packw_k<<<cdiv(294912, 256), 256, 0, stream>>>(w5, w5p, 128, 256);
  packw_k<<<cdiv(147456, 256), 256, 0, stream>>>(w6, w6p, 128, 128);
  packw_k<<<cdiv(73728, 256), 256, 0, stream>>>(w7, w7p, 64, 128);
  packw_k<<<cdiv(36864, 256), 256, 0, stream>>>(w8, w8p, 64, 64);
  packwf_k<<<36, 256, 0, stream>>>(wf, wfp);

  // ---- @64 ----
  conv_mfma_k<16, 2, 1><<<dim3(1, 32, 16), 256, 0, stream>>>(
      XN, w1p, b1, A1, 256, 64, 64, 0, 64, 0, 64, 0, 64);
  hipMemsetAsync(Ssum, 0, 65536, stream);
  sn_sum_k<<<4 * 32, 256, 0, stream>>>(A1, seg, Ssum, Qsum, 256, 6, 32);
  sn_fin_k<<<1, 1024, 0, stream>>>(Ssum, Qsum, RS, KK, 256, 1.f / 4096.f);
  up2norm_k<<<cdiv(4 * 128 * 128 * 32, 256), 256, 0, stream>>>(A1, seg, RS, KK, U1, 256, 6, 0, 128);

  // ---- @128 ----
  conv_mfma_k<8, 4, 1><<<dim3(2, 32, 16), 256, 0, stream>>>(
      U1, w2p, b2, C2, 256, 128, 128, 0, 128, 0, 128, 0, 128);
  conv_mfma_k<8, 4, 1><<<dim3(2, 32, 16), 256, 0, stream>>>(
      C2, w3p, b3, C3, 256, 128, 128, 0, 128, 0, 128, 0, 128);
  conv_mfma_k<8, 4, 1><<<dim3(2, 32, 16), 256, 0, stream>>>(
      C3, w4p, b4, C4, 256, 128, 128, 0, 128, 0, 128, 0, 128);
  conv_mfma_k<8, 4, 1><<<dim3(2, 32, 8), 256, 0, stream>>>(
      C4, w5p, b5, C5, 128, 128, 128, 0, 128, 0, 128, 0, 128);
  hipMemsetAsync(Ssum, 0, 65536, stream);
  sn_sum_k<<<4 * 64, 256, 0, stream>>>(C5, seg, Ssum, Qsum, 128, 7, 64);
  sn_fin_k<<<1, 512, 0, stream>>>(Ssum, Qsum, RS, KK, 128, 1.f / 16384.f);

  // ---- @256, 2 bands: up2norm -> conv6 -> conv7 ----
  for (int kb = 0; kb < 2; ++kb) {
    const int r0 = kb * 128;
    const int Rlo = max(r0 - 1, 0), Rhi = min(r0 + 128, 255);
    const int rows6 = Rhi - Rlo + 1;
    const int Ulo = max(Rlo - 1, 0), Uhi = min(Rhi + 1, 255);
    const int rowsU = Uhi - Ulo + 1;
    up2norm_k<<<cdiv(4 * rowsU * 256 * 16, 256), 256, 0, stream>>>(C5, seg, RS, KK, U6, 128, 7, Ulo, rowsU);
    conv_mfma_k<4, 4, 1><<<dim3(4, cdiv(rows6, 4), 8), 256, 0, stream>>>(
        U6, w6p, b6, C6, 128, 256, 256, Ulo, rowsU, Rlo, rows6, Rlo, rows6);
    conv_mfma_k<4, 4, 1><<<dim3(4, 32, 4), 256, 0, stream>>>(
        C6, w7p, b7, C7, 64, 256, 256, Rlo, rows6, r0, 128, 0, 256);
  }
  hipMemsetAsync(Ssum, 0, 65536, stream);
  sn_sum_k<<<4 * 128, 256, 0, stream>>>(C7, seg, Ssum, Qsum, 64, 8, 128);
  sn_fin_k<<<1, 256, 0, stream>>>(Ssum, Qsum, RS, KK, 64, 1.f / 65536.f);

  // ---- @512, 4 bands: up2norm -> conv8 -> convf ----
  for (int kb = 0; kb < 4; ++kb) {
    const int r0 = kb * 128;
    const int Rlo = max(r0 - 1, 0), Rhi = min(r0 + 128, 511);
    const int rows8 = Rhi - Rlo + 1;
    const int Ulo = max(Rlo - 1, 0), Uhi = min(Rhi + 1, 511);
    const int rowsU = Uhi - Ulo + 1;
    up2norm_k<<<cdiv(4 * rowsU * 512 * 8, 256), 256, 0, stream>>>(C7, seg, RS, KK, U8, 64, 8, Ulo, rowsU);
    conv_mfma_k<2, 4, 1><<<dim3(8, cdiv(rows8, 4), 4), 256, 0, stream>>>(
        U8, w8p, b8, C8, 64, 512, 512, Ulo, rowsU, Rlo, rows8, Rlo, rows8);
    convf_mfma_k<<<dim3(8, 32, 4), 256, 0, stream>>>(C8, wfp, bf, outp, Rlo, rows8, r0, 128);
  }
}